// Round 1
// baseline (2664.564 us; speedup 1.0000x reference)
//
#include <hip/hip_runtime.h>

// Problem constants (from reference)
constexpr int NN  = 50000;   // nodes
constexpr int NE  = 800000;  // edges
constexpr int DIN = 96;      // input feature dim
constexpr int HID = 128;     // hidden dim
constexpr int NG  = 256;     // graphs

// ---------------------------------------------------------------------------
// zero-fill (ws is poisoned 0xAA each call; agg buffers need zeros)
// ---------------------------------------------------------------------------
__global__ void zero_kernel(float4* __restrict__ p, int n4) {
    int i = blockIdx.x * blockDim.x + threadIdx.x;
    if (i < n4) p[i] = make_float4(0.f, 0.f, 0.f, 0.f);
}

// ---------------------------------------------------------------------------
// transpose W[rows][cols] -> WT[cols][rows] (tiny, one-shot per launch)
// ---------------------------------------------------------------------------
__global__ void transpose_kernel(const float* __restrict__ src,
                                 float* __restrict__ dst, int rows, int cols) {
    int i = blockIdx.x * blockDim.x + threadIdx.x;
    if (i >= rows * cols) return;
    int r = i / cols, c = i - r * cols;
    dst[c * rows + r] = src[i];
}

// ---------------------------------------------------------------------------
// conv1 edge scatter: agg1[dst] += w_e * x[src]   (96 feats, float4 chunks)
// thread i -> edge e = i/24, quad q = i%24
// ---------------------------------------------------------------------------
__global__ void scatter1_kernel(const float* __restrict__ x,
                                const int* __restrict__ ei,
                                const float* __restrict__ ea,
                                float* __restrict__ agg) {
    int i = blockIdx.x * blockDim.x + threadIdx.x;
    if (i >= NE * 24) return;
    int e = i / 24;
    int q = i - e * 24;
    int src = ei[e];
    int dst = ei[NE + e];
    float w = ea[e];
    float4 v = ((const float4*)x)[src * 24 + q];
    float* p = agg + (size_t)dst * DIN + q * 4;
    atomicAdd(p + 0, v.x * w);
    atomicAdd(p + 1, v.y * w);
    atomicAdd(p + 2, v.z * w);
    atomicAdd(p + 3, v.w * w);
}

// ---------------------------------------------------------------------------
// conv3 edge scatter: agg3[dst] += w_e * h1[src]  (128 feats, float4 chunks)
// ---------------------------------------------------------------------------
__global__ void scatter3_kernel(const float* __restrict__ h1,
                                const int* __restrict__ ei,
                                const float* __restrict__ ea,
                                float* __restrict__ agg) {
    int i = blockIdx.x * blockDim.x + threadIdx.x;
    if (i >= NE * 32) return;
    int e = i >> 5;
    int q = i & 31;
    int src = ei[e];
    int dst = ei[NE + e];
    float w = ea[e];
    float4 v = ((const float4*)h1)[src * 32 + q];
    float* p = agg + (size_t)dst * HID + q * 4;
    atomicAdd(p + 0, v.x * w);
    atomicAdd(p + 1, v.y * w);
    atomicAdd(p + 2, v.z * w);
    atomicAdd(p + 3, v.w * w);
}

// ---------------------------------------------------------------------------
// conv1 GEMM: h1 = relu(agg1 @ Wrel1^T + b1 + x @ Wroot1^T)
// Weights pre-transposed to [k][f] so reads are coalesced (L1/L2 resident).
// Block: 256 threads; per iteration 8 nodes; thread = (node nn, feat-quad fq);
// per k: 2 global b128 (weights, shared across nn -> L1 hits) + 2 LDS
// broadcasts + 8 FMA.
// ---------------------------------------------------------------------------
__launch_bounds__(256)
__global__ void conv1_kernel(const float* __restrict__ x,
                             const float* __restrict__ agg,
                             const float* __restrict__ WrelT,   // [DIN][HID]
                             const float* __restrict__ WrootT,  // [DIN][HID]
                             const float* __restrict__ brel,
                             float* __restrict__ h1) {
    __shared__ float sx[8][DIN];
    __shared__ float sa[8][DIN];
    const int nn = threadIdx.x >> 5;   // 0..7  node within group
    const int fq = threadIdx.x & 31;   // 0..31 feature quad

    for (int base = blockIdx.x * 8; base < NN; base += gridDim.x * 8) {
        __syncthreads();   // previous iteration's reads done
        for (int j = threadIdx.x; j < 8 * 2 * DIN; j += 256) {
            int node = j / (2 * DIN);
            int r = j - node * (2 * DIN);
            int n = base + node;
            if (r < DIN) sx[node][r]       = x[(size_t)n * DIN + r];
            else         sa[node][r - DIN] = agg[(size_t)n * DIN + (r - DIN)];
        }
        __syncthreads();

        float4 acc = ((const float4*)brel)[fq];
        #pragma unroll 8
        for (int k = 0; k < DIN; ++k) {
            float4 wr = ((const float4*)WrelT)[k * 32 + fq];
            float4 wo = ((const float4*)WrootT)[k * 32 + fq];
            float a = sa[nn][k];
            float b = sx[nn][k];
            acc.x = fmaf(a, wr.x, fmaf(b, wo.x, acc.x));
            acc.y = fmaf(a, wr.y, fmaf(b, wo.y, acc.y));
            acc.z = fmaf(a, wr.z, fmaf(b, wo.z, acc.z));
            acc.w = fmaf(a, wr.w, fmaf(b, wo.w, acc.w));
        }
        acc.x = fmaxf(acc.x, 0.f);
        acc.y = fmaxf(acc.y, 0.f);
        acc.z = fmaxf(acc.z, 0.f);
        acc.w = fmaxf(acc.w, 0.f);
        int n = base + nn;   // NN % 8 == 0, always in range
        ((float4*)h1)[(size_t)n * 32 + fq] = acc;
    }
}

// ---------------------------------------------------------------------------
// Fused per-graph reduce + conv3 GEMM + mean + linear head.
// pooled_g = (Wrel3 @ S2_g + Wroot3 @ S1_g)/n_g + b3 ; out = relu(Wlin.pooled+blin)
// where S1_g = sum h1 rows in g, S2_g = sum agg3 rows in g (batch is sorted).
// One block per graph, 128 threads (one per hidden feature).
// ---------------------------------------------------------------------------
__launch_bounds__(128)
__global__ void pool_final_kernel(const float* __restrict__ h1,
                                  const float* __restrict__ agg3,
                                  const int* __restrict__ batch,
                                  const float* __restrict__ WrelT3,  // [HID][HID] transposed
                                  const float* __restrict__ WrootT3, // [HID][HID] transposed
                                  const float* __restrict__ brel3,
                                  const float* __restrict__ Wlin,
                                  const float* __restrict__ blin,
                                  float* __restrict__ out) {
    int g = blockIdx.x;
    int f = threadIdx.x;

    // lower_bound(batch, g), lower_bound(batch, g+1)  (batch sorted asc)
    int lo = 0, hi = NN;
    while (lo < hi) { int m = (lo + hi) >> 1; if (batch[m] < g) lo = m + 1; else hi = m; }
    int start = lo;
    hi = NN;
    while (lo < hi) { int m = (lo + hi) >> 1; if (batch[m] < g + 1) lo = m + 1; else hi = m; }
    int end = lo;
    int n = end - start;

    float s1 = 0.f, s2 = 0.f;
    for (int i = start; i < end; ++i) {
        s1 += h1[(size_t)i * HID + f];
        s2 += agg3[(size_t)i * HID + f];
    }
    __shared__ float sS1[HID], sS2[HID];
    __shared__ float sred[2];
    sS1[f] = s1;
    sS2[f] = s2;
    __syncthreads();

    float pooled = 0.f;
    if (n > 0) {
        float acc = 0.f;
        #pragma unroll 8
        for (int k = 0; k < HID; ++k) {
            acc = fmaf(WrelT3[k * HID + f], sS2[k], acc);
            acc = fmaf(WrootT3[k * HID + f], sS1[k], acc);
        }
        pooled = acc / (float)n + brel3[f];
    }

    float z = pooled * Wlin[f];
    #pragma unroll
    for (int off = 32; off > 0; off >>= 1) z += __shfl_down(z, off, 64);
    if ((f & 63) == 0) sred[f >> 6] = z;
    __syncthreads();
    if (f == 0) out[g] = fmaxf(sred[0] + sred[1] + blin[0], 0.f);
}

// ---------------------------------------------------------------------------
extern "C" void kernel_launch(void* const* d_in, const int* in_sizes, int n_in,
                              void* d_out, int out_size, void* d_ws, size_t ws_size,
                              hipStream_t stream) {
    const float* x      = (const float*)d_in[0];
    const int*   ei     = (const int*)  d_in[1];   // [2, NE]
    const int*   batch  = (const int*)  d_in[2];
    const float* ea     = (const float*)d_in[3];
    const float* Wrel1  = (const float*)d_in[4];   // [HID, DIN]
    const float* brel1  = (const float*)d_in[5];
    const float* Wroot1 = (const float*)d_in[6];   // [HID, DIN]
    const float* Wrel3  = (const float*)d_in[7];   // [HID, HID]
    const float* brel3  = (const float*)d_in[8];
    const float* Wroot3 = (const float*)d_in[9];   // [HID, HID]
    const float* Wlin   = (const float*)d_in[10];  // [1, HID]
    const float* blin   = (const float*)d_in[11];
    float* out = (float*)d_out;

    // workspace layout (floats)
    float* ws = (float*)d_ws;
    float* agg1   = ws;                                  // NN*DIN = 4,800,000
    float* agg3   = agg1 + (size_t)NN * DIN;             // NN*HID = 6,400,000
    float* h1     = agg3 + (size_t)NN * HID;             // NN*HID = 6,400,000
    float* WrelT1 = h1 + (size_t)NN * HID;               // 12,288
    float* WrootT1= WrelT1 + DIN * HID;                  // 12,288
    float* WrelT3 = WrootT1 + DIN * HID;                 // 16,384
    float* WrootT3= WrelT3 + HID * HID;                  // 16,384

    // zero agg1+agg3 (contiguous)
    int zero_n4 = (NN * DIN + NN * HID) / 4;             // 2,800,000 float4
    zero_kernel<<<(zero_n4 + 255) / 256, 256, 0, stream>>>((float4*)ws, zero_n4);

    // one-shot weight transposes (tiny)
    transpose_kernel<<<(HID * DIN + 255) / 256, 256, 0, stream>>>(Wrel1,  WrelT1,  HID, DIN);
    transpose_kernel<<<(HID * DIN + 255) / 256, 256, 0, stream>>>(Wroot1, WrootT1, HID, DIN);
    transpose_kernel<<<(HID * HID + 255) / 256, 256, 0, stream>>>(Wrel3,  WrelT3,  HID, HID);
    transpose_kernel<<<(HID * HID + 255) / 256, 256, 0, stream>>>(Wroot3, WrootT3, HID, HID);

    // conv1 aggregation (atomic scatter)
    scatter1_kernel<<<(NE * 24 + 255) / 256, 256, 0, stream>>>(x, ei, ea, agg1);

    // conv1 GEMM + bias + relu
    conv1_kernel<<<2048, 256, 0, stream>>>(x, agg1, WrelT1, WrootT1, brel1, h1);

    // conv3 aggregation (atomic scatter)
    scatter3_kernel<<<(NE * 32 + 255) / 256, 256, 0, stream>>>(h1, ei, ea, agg3);

    // fused segment-sum + conv3 GEMM + mean pool + linear + relu
    pool_final_kernel<<<NG, 128, 0, stream>>>(h1, agg3, batch, WrelT3, WrootT3,
                                              brel3, Wlin, blin, out);
}

// Round 2
// 655.494 us; speedup vs baseline: 4.0650x; 4.0650x over previous
//
#include <hip/hip_runtime.h>

// Problem constants (from reference)
constexpr int NN  = 50000;   // nodes
constexpr int NE  = 800000;  // edges
constexpr int DIN = 96;      // input feature dim
constexpr int HID = 128;     // hidden dim
constexpr int NG  = 256;     // graphs

// ---------------------------------------------------------------------------
// zero-fill ints (deg histogram needs zeros; ws is poisoned 0xAA)
// ---------------------------------------------------------------------------
__global__ void zero_int_kernel(int* __restrict__ p, int n) {
    int i = blockIdx.x * blockDim.x + threadIdx.x;
    if (i < n) p[i] = 0;
}

// ---------------------------------------------------------------------------
// transpose W[rows][cols] -> WT[cols][rows] (tiny, one-shot per launch)
// ---------------------------------------------------------------------------
__global__ void transpose_kernel(const float* __restrict__ src,
                                 float* __restrict__ dst, int rows, int cols) {
    int i = blockIdx.x * blockDim.x + threadIdx.x;
    if (i >= rows * cols) return;
    int r = i / cols, c = i - r * cols;
    dst[c * rows + r] = src[i];
}

// ---------------------------------------------------------------------------
// CSR build step 1: in-degree histogram over dst
// ---------------------------------------------------------------------------
__global__ void hist_kernel(const int* __restrict__ ei, int* __restrict__ deg) {
    int e = blockIdx.x * blockDim.x + threadIdx.x;
    if (e < NE) atomicAdd(&deg[ei[NE + e]], 1);
}

// ---------------------------------------------------------------------------
// CSR build step 2: single-block exclusive scan of deg -> row_ptr (+cursor copy)
// 1024 threads, each handles ITEMS contiguous elements.
// ---------------------------------------------------------------------------
__launch_bounds__(1024)
__global__ void scan_kernel(const int* __restrict__ deg,
                            int* __restrict__ row_ptr,
                            int* __restrict__ cursor) {
    constexpr int ITEMS = (NN + 1023) / 1024;  // 49
    __shared__ int part[1024];
    int t = threadIdx.x;
    int start = t * ITEMS;
    int sum = 0;
    for (int i = 0; i < ITEMS; ++i) {
        int idx = start + i;
        if (idx < NN) sum += deg[idx];
    }
    part[t] = sum;
    __syncthreads();
    // Hillis-Steele inclusive scan over 1024 partials
    for (int off = 1; off < 1024; off <<= 1) {
        int v = (t >= off) ? part[t - off] : 0;
        __syncthreads();
        part[t] += v;
        __syncthreads();
    }
    int run = (t == 0) ? 0 : part[t - 1];  // exclusive prefix of this chunk
    for (int i = 0; i < ITEMS; ++i) {
        int idx = start + i;
        if (idx < NN) {
            row_ptr[idx] = run;
            cursor[idx]  = run;
            run += deg[idx];
        }
    }
    if (t == 1023) row_ptr[NN] = part[1023];  // == NE
}

// ---------------------------------------------------------------------------
// CSR build step 3: fill edge arrays grouped by dst (order within row arbitrary)
// ---------------------------------------------------------------------------
__global__ void fill_kernel(const int* __restrict__ ei, const float* __restrict__ ea,
                            int* __restrict__ cursor,
                            int* __restrict__ csr_src, float* __restrict__ csr_w) {
    int e = blockIdx.x * blockDim.x + threadIdx.x;
    if (e >= NE) return;
    int dst = ei[NE + e];
    int pos = atomicAdd(&cursor[dst], 1);
    csr_src[pos] = ei[e];
    csr_w[pos]   = ea[e];
}

// ---------------------------------------------------------------------------
// conv1 aggregation, gather form: agg1[n] = sum_{e: dst=n} w_e * x[src_e]
// 32 lanes per node, each lane owns 3 of 96 features. No atomics.
// ---------------------------------------------------------------------------
__launch_bounds__(256)
__global__ void gather1_kernel(const float* __restrict__ x,
                               const int* __restrict__ row_ptr,
                               const int* __restrict__ csr_src,
                               const float* __restrict__ csr_w,
                               float* __restrict__ agg) {
    int node = blockIdx.x * 8 + (threadIdx.x >> 5);
    int lane = threadIdx.x & 31;
    if (node >= NN) return;
    int s = row_ptr[node], t = row_ptr[node + 1];
    float a0 = 0.f, a1 = 0.f, a2 = 0.f;
    for (int j = s; j < t; ++j) {
        int src = csr_src[j];          // broadcast within 32-lane group
        float w = csr_w[j];
        const float* xp = x + (size_t)src * DIN + lane;
        a0 = fmaf(w, xp[0],  a0);
        a1 = fmaf(w, xp[32], a1);
        a2 = fmaf(w, xp[64], a2);
    }
    float* ap = agg + (size_t)node * DIN + lane;
    ap[0]  = a0;
    ap[32] = a1;
    ap[64] = a2;
}

// ---------------------------------------------------------------------------
// conv3 aggregation, gather form: agg3[n] = sum_{e: dst=n} w_e * h1[src_e]
// 32 lanes per node, float4 per lane (128 feats). No atomics.
// ---------------------------------------------------------------------------
__launch_bounds__(256)
__global__ void gather3_kernel(const float* __restrict__ h1,
                               const int* __restrict__ row_ptr,
                               const int* __restrict__ csr_src,
                               const float* __restrict__ csr_w,
                               float* __restrict__ agg) {
    int node = blockIdx.x * 8 + (threadIdx.x >> 5);
    int lane = threadIdx.x & 31;
    if (node >= NN) return;
    int s = row_ptr[node], t = row_ptr[node + 1];
    float4 acc = make_float4(0.f, 0.f, 0.f, 0.f);
    const float4* h4 = (const float4*)h1;
    for (int j = s; j < t; ++j) {
        int src = csr_src[j];
        float w = csr_w[j];
        float4 v = h4[(size_t)src * 32 + lane];
        acc.x = fmaf(w, v.x, acc.x);
        acc.y = fmaf(w, v.y, acc.y);
        acc.z = fmaf(w, v.z, acc.z);
        acc.w = fmaf(w, v.w, acc.w);
    }
    ((float4*)agg)[(size_t)node * 32 + lane] = acc;
}

// ---------------------------------------------------------------------------
// conv1 GEMM: h1 = relu(agg1 @ Wrel1^T + b1 + x @ Wroot1^T)
// ---------------------------------------------------------------------------
__launch_bounds__(256)
__global__ void conv1_kernel(const float* __restrict__ x,
                             const float* __restrict__ agg,
                             const float* __restrict__ WrelT,   // [DIN][HID]
                             const float* __restrict__ WrootT,  // [DIN][HID]
                             const float* __restrict__ brel,
                             float* __restrict__ h1) {
    __shared__ float sx[8][DIN];
    __shared__ float sa[8][DIN];
    const int nn = threadIdx.x >> 5;   // 0..7  node within group
    const int fq = threadIdx.x & 31;   // 0..31 feature quad

    for (int base = blockIdx.x * 8; base < NN; base += gridDim.x * 8) {
        __syncthreads();   // previous iteration's reads done
        for (int j = threadIdx.x; j < 8 * 2 * DIN; j += 256) {
            int node = j / (2 * DIN);
            int r = j - node * (2 * DIN);
            int n = base + node;
            if (r < DIN) sx[node][r]       = x[(size_t)n * DIN + r];
            else         sa[node][r - DIN] = agg[(size_t)n * DIN + (r - DIN)];
        }
        __syncthreads();

        float4 acc = ((const float4*)brel)[fq];
        #pragma unroll 8
        for (int k = 0; k < DIN; ++k) {
            float4 wr = ((const float4*)WrelT)[k * 32 + fq];
            float4 wo = ((const float4*)WrootT)[k * 32 + fq];
            float a = sa[nn][k];
            float b = sx[nn][k];
            acc.x = fmaf(a, wr.x, fmaf(b, wo.x, acc.x));
            acc.y = fmaf(a, wr.y, fmaf(b, wo.y, acc.y));
            acc.z = fmaf(a, wr.z, fmaf(b, wo.z, acc.z));
            acc.w = fmaf(a, wr.w, fmaf(b, wo.w, acc.w));
        }
        acc.x = fmaxf(acc.x, 0.f);
        acc.y = fmaxf(acc.y, 0.f);
        acc.z = fmaxf(acc.z, 0.f);
        acc.w = fmaxf(acc.w, 0.f);
        int n = base + nn;   // NN % 8 == 0, always in range
        ((float4*)h1)[(size_t)n * 32 + fq] = acc;
    }
}

// ---------------------------------------------------------------------------
// Fused per-graph reduce + conv3 GEMM + mean + linear head.
// ---------------------------------------------------------------------------
__launch_bounds__(128)
__global__ void pool_final_kernel(const float* __restrict__ h1,
                                  const float* __restrict__ agg3,
                                  const int* __restrict__ batch,
                                  const float* __restrict__ WrelT3,  // [HID][HID]
                                  const float* __restrict__ WrootT3, // [HID][HID]
                                  const float* __restrict__ brel3,
                                  const float* __restrict__ Wlin,
                                  const float* __restrict__ blin,
                                  float* __restrict__ out) {
    int g = blockIdx.x;
    int f = threadIdx.x;

    // lower_bound(batch, g), lower_bound(batch, g+1)  (batch sorted asc)
    int lo = 0, hi = NN;
    while (lo < hi) { int m = (lo + hi) >> 1; if (batch[m] < g) lo = m + 1; else hi = m; }
    int start = lo;
    hi = NN;
    while (lo < hi) { int m = (lo + hi) >> 1; if (batch[m] < g + 1) lo = m + 1; else hi = m; }
    int end = lo;
    int n = end - start;

    float s1 = 0.f, s2 = 0.f;
    for (int i = start; i < end; ++i) {
        s1 += h1[(size_t)i * HID + f];
        s2 += agg3[(size_t)i * HID + f];
    }
    __shared__ float sS1[HID], sS2[HID];
    __shared__ float sred[2];
    sS1[f] = s1;
    sS2[f] = s2;
    __syncthreads();

    float pooled = 0.f;
    if (n > 0) {
        float acc = 0.f;
        #pragma unroll 8
        for (int k = 0; k < HID; ++k) {
            acc = fmaf(WrelT3[k * HID + f], sS2[k], acc);
            acc = fmaf(WrootT3[k * HID + f], sS1[k], acc);
        }
        pooled = acc / (float)n + brel3[f];
    }

    float z = pooled * Wlin[f];
    #pragma unroll
    for (int off = 32; off > 0; off >>= 1) z += __shfl_down(z, off, 64);
    if ((f & 63) == 0) sred[f >> 6] = z;
    __syncthreads();
    if (f == 0) out[g] = fmaxf(sred[0] + sred[1] + blin[0], 0.f);
}

// ---------------------------------------------------------------------------
extern "C" void kernel_launch(void* const* d_in, const int* in_sizes, int n_in,
                              void* d_out, int out_size, void* d_ws, size_t ws_size,
                              hipStream_t stream) {
    const float* x      = (const float*)d_in[0];
    const int*   ei     = (const int*)  d_in[1];   // [2, NE]
    const int*   batch  = (const int*)  d_in[2];
    const float* ea     = (const float*)d_in[3];
    const float* Wrel1  = (const float*)d_in[4];   // [HID, DIN]
    const float* brel1  = (const float*)d_in[5];
    const float* Wroot1 = (const float*)d_in[6];   // [HID, DIN]
    const float* Wrel3  = (const float*)d_in[7];   // [HID, HID]
    const float* brel3  = (const float*)d_in[8];
    const float* Wroot3 = (const float*)d_in[9];   // [HID, HID]
    const float* Wlin   = (const float*)d_in[10];  // [1, HID]
    const float* blin   = (const float*)d_in[11];
    float* out = (float*)d_out;

    // workspace layout (floats / ints, all 16B-aligned offsets)
    // Region A is shared by agg1 (first NN*DIN) and agg3 (all NN*HID):
    // conv1 consumes agg1 before gather3 writes agg3 (stream-ordered).
    float* ws = (float*)d_ws;
    float* aggA    = ws;                                   // max = NN*HID = 6,400,000
    float* h1      = aggA + (size_t)NN * HID;              // 6,400,000
    float* WrelT1  = h1 + (size_t)NN * HID;                // 12,288
    float* WrootT1 = WrelT1 + DIN * HID;                   // 12,288
    float* WrelT3  = WrootT1 + DIN * HID;                  // 16,384
    float* WrootT3 = WrelT3 + HID * HID;                   // 16,384
    float* csr_w   = WrootT3 + HID * HID;                  // NE = 800,000
    int*   csr_src = (int*)(csr_w + NE);                   // NE = 800,000
    int*   row_ptr = csr_src + NE;                         // NN+1
    int*   deg     = row_ptr + NN + 4;                     // NN (deg doubles as hist)
    int*   cursor  = deg + NN;                             // NN
    // total ~58.4 MB (< previous round's 70.6 MB which fit)

    float* agg1 = aggA;
    float* agg3 = aggA;

    // --- CSR build ---
    zero_int_kernel<<<(NN + 255) / 256, 256, 0, stream>>>(deg, NN);
    hist_kernel<<<(NE + 255) / 256, 256, 0, stream>>>(ei, deg);
    scan_kernel<<<1, 1024, 0, stream>>>(deg, row_ptr, cursor);
    fill_kernel<<<(NE + 255) / 256, 256, 0, stream>>>(ei, ea, cursor, csr_src, csr_w);

    // --- weight transposes (tiny) ---
    transpose_kernel<<<(HID * DIN + 255) / 256, 256, 0, stream>>>(Wrel1,  WrelT1,  HID, DIN);
    transpose_kernel<<<(HID * DIN + 255) / 256, 256, 0, stream>>>(Wroot1, WrootT1, HID, DIN);
    transpose_kernel<<<(HID * HID + 255) / 256, 256, 0, stream>>>(Wrel3,  WrelT3,  HID, HID);
    transpose_kernel<<<(HID * HID + 255) / 256, 256, 0, stream>>>(Wroot3, WrootT3, HID, HID);

    // --- conv1 aggregation (gather, no atomics) ---
    gather1_kernel<<<(NN + 7) / 8, 256, 0, stream>>>(x, row_ptr, csr_src, csr_w, agg1);

    // --- conv1 GEMM + bias + relu ---
    conv1_kernel<<<2048, 256, 0, stream>>>(x, agg1, WrelT1, WrootT1, brel1, h1);

    // --- conv3 aggregation (gather, no atomics) ---
    gather3_kernel<<<(NN + 7) / 8, 256, 0, stream>>>(h1, row_ptr, csr_src, csr_w, agg3);

    // --- fused segment-sum + conv3 GEMM + mean pool + linear + relu ---
    pool_final_kernel<<<NG, 128, 0, stream>>>(h1, agg3, batch, WrelT3, WrootT3,
                                              brel3, Wlin, blin, out);
}

// Round 3
// 423.628 us; speedup vs baseline: 6.2899x; 1.5473x over previous
//
#include <hip/hip_runtime.h>

// Problem constants (from reference)
constexpr int NN  = 50000;   // nodes
constexpr int NE  = 800000;  // edges
constexpr int DIN = 96;      // input feature dim
constexpr int HID = 128;     // hidden dim
constexpr int NG  = 256;     // graphs

constexpr int NBE = 256;     // blocks for edge reduction
constexpr int NBN = 64;      // blocks for node reduction

// ---------------------------------------------------------------------------
// zero-fill ints (deg histogram needs zeros; ws is poisoned 0xAA)
// ---------------------------------------------------------------------------
__global__ void zero_int_kernel(int* __restrict__ p, int n) {
    int i = blockIdx.x * blockDim.x + threadIdx.x;
    if (i < n) p[i] = 0;
}

// ---------------------------------------------------------------------------
// transpose W[rows][cols] -> WT[cols][rows] (tiny, one-shot per launch)
// ---------------------------------------------------------------------------
__global__ void transpose_kernel(const float* __restrict__ src,
                                 float* __restrict__ dst, int rows, int cols) {
    int i = blockIdx.x * blockDim.x + threadIdx.x;
    if (i >= rows * cols) return;
    int r = i / cols, c = i - r * cols;
    dst[c * rows + r] = src[i];
}

// ---------------------------------------------------------------------------
// u_k = sum_f Wlin[f] * Wrel3[f][k];  v_k = sum_f Wlin[f] * Wroot3[f][k]
// c0 = Wlin . b3   (128 threads, one block)
// ---------------------------------------------------------------------------
__global__ void uv_kernel(const float* __restrict__ Wrel3,
                          const float* __restrict__ Wroot3,
                          const float* __restrict__ Wlin,
                          const float* __restrict__ b3,
                          float* __restrict__ u, float* __restrict__ v,
                          float* __restrict__ c0) {
    int k = threadIdx.x;
    float su = 0.f, sv = 0.f;
    for (int f = 0; f < HID; ++f) {
        float wl = Wlin[f];
        su = fmaf(wl, Wrel3[f * HID + k], su);
        sv = fmaf(wl, Wroot3[f * HID + k], sv);
    }
    u[k] = su;
    v[k] = sv;
    if (k == 0) {
        float c = 0.f;
        for (int f = 0; f < HID; ++f) c = fmaf(Wlin[f], b3[f], c);
        c0[0] = c;
    }
}

// ---------------------------------------------------------------------------
// CSR build step 1: in-degree histogram over dst
// ---------------------------------------------------------------------------
__global__ void hist_kernel(const int* __restrict__ ei, int* __restrict__ deg) {
    int e = blockIdx.x * blockDim.x + threadIdx.x;
    if (e < NE) atomicAdd(&deg[ei[NE + e]], 1);
}

// ---------------------------------------------------------------------------
// CSR build step 2: single-block exclusive scan of deg -> row_ptr (+cursor)
// ---------------------------------------------------------------------------
__launch_bounds__(1024)
__global__ void scan_kernel(const int* __restrict__ deg,
                            int* __restrict__ row_ptr,
                            int* __restrict__ cursor) {
    constexpr int ITEMS = (NN + 1023) / 1024;  // 49
    __shared__ int part[1024];
    int t = threadIdx.x;
    int start = t * ITEMS;
    int sum = 0;
    for (int i = 0; i < ITEMS; ++i) {
        int idx = start + i;
        if (idx < NN) sum += deg[idx];
    }
    part[t] = sum;
    __syncthreads();
    for (int off = 1; off < 1024; off <<= 1) {
        int vv = (t >= off) ? part[t - off] : 0;
        __syncthreads();
        part[t] += vv;
        __syncthreads();
    }
    int run = (t == 0) ? 0 : part[t - 1];
    for (int i = 0; i < ITEMS; ++i) {
        int idx = start + i;
        if (idx < NN) {
            row_ptr[idx] = run;
            cursor[idx]  = run;
            run += deg[idx];
        }
    }
    if (t == 1023) row_ptr[NN] = part[1023];  // == NE
}

// ---------------------------------------------------------------------------
// CSR build step 3: fill (src, weight) pairs grouped by dst, packed 8B
// ---------------------------------------------------------------------------
__global__ void fill_kernel(const int* __restrict__ ei, const float* __restrict__ ea,
                            int* __restrict__ cursor, int2* __restrict__ csr_sw) {
    int e = blockIdx.x * blockDim.x + threadIdx.x;
    if (e >= NE) return;
    int dst = ei[NE + e];
    int pos = atomicAdd(&cursor[dst], 1);
    csr_sw[pos] = make_int2(ei[e], __float_as_int(ea[e]));
}

// ---------------------------------------------------------------------------
// conv1 aggregation, gather form: agg1[n] = sum_{e: dst=n} w_e * x[src_e]
// 32 lanes per node, 3 feats/lane, 2-edge unroll for MLP. No atomics.
// ---------------------------------------------------------------------------
__launch_bounds__(256)
__global__ void gather1_kernel(const float* __restrict__ x,
                               const int* __restrict__ row_ptr,
                               const int2* __restrict__ csr_sw,
                               float* __restrict__ agg) {
    int node = blockIdx.x * 8 + (threadIdx.x >> 5);
    int lane = threadIdx.x & 31;
    if (node >= NN) return;
    int s = row_ptr[node], t = row_ptr[node + 1];
    float a0 = 0.f, a1 = 0.f, a2 = 0.f;
    int j = s;
    for (; j + 1 < t; j += 2) {
        int2 e0 = csr_sw[j];
        int2 e1 = csr_sw[j + 1];
        float w0 = __int_as_float(e0.y);
        float w1 = __int_as_float(e1.y);
        const float* x0 = x + (size_t)e0.x * DIN + lane;
        const float* x1 = x + (size_t)e1.x * DIN + lane;
        a0 = fmaf(w0, x0[0],  a0);
        a1 = fmaf(w0, x0[32], a1);
        a2 = fmaf(w0, x0[64], a2);
        a0 = fmaf(w1, x1[0],  a0);
        a1 = fmaf(w1, x1[32], a1);
        a2 = fmaf(w1, x1[64], a2);
    }
    if (j < t) {
        int2 e0 = csr_sw[j];
        float w0 = __int_as_float(e0.y);
        const float* x0 = x + (size_t)e0.x * DIN + lane;
        a0 = fmaf(w0, x0[0],  a0);
        a1 = fmaf(w0, x0[32], a1);
        a2 = fmaf(w0, x0[64], a2);
    }
    float* ap = agg + (size_t)node * DIN + lane;
    ap[0]  = a0;
    ap[32] = a1;
    ap[64] = a2;
}

// ---------------------------------------------------------------------------
// conv1 GEMM + relu + projection to scalars:
//   h1row = relu(agg1 @ Wrel1^T + b1 + x @ Wroot1^T)   (in registers only)
//   p[n] = u . h1row ; q[n] = v . h1row
// Block = 256 threads; 32 nodes/block; thread = (nn: 4 nodes, fq: 4 feats).
// Per 4-k step: 128 FMA vs 8 global b128 (weights) + 8 ds b128.
// ---------------------------------------------------------------------------
__launch_bounds__(256)
__global__ void conv1_kernel(const float* __restrict__ x,
                             const float* __restrict__ agg,
                             const float* __restrict__ WrelT,   // [DIN][HID]
                             const float* __restrict__ WrootT,  // [DIN][HID]
                             const float* __restrict__ brel,
                             const float* __restrict__ u,
                             const float* __restrict__ v,
                             float* __restrict__ p,
                             float* __restrict__ q) {
    __shared__ float sx[32][DIN];
    __shared__ float sa[32][DIN];
    const int tid = threadIdx.x;
    const int nn = tid >> 5;     // 0..7, owns nodes 4nn..4nn+3
    const int fq = tid & 31;     // feature quad 0..31
    const int base = blockIdx.x * 32;

    // stage 32 nodes of x and agg (24 float4 per row each)
    for (int j = tid; j < 32 * 48; j += 256) {
        int node = j / 48;
        int r = j - node * 48;
        int n = base + node;
        if (n < NN) {
            if (r < 24) ((float4*)sx[node])[r]      = ((const float4*)(x   + (size_t)n * DIN))[r];
            else        ((float4*)sa[node])[r - 24] = ((const float4*)(agg + (size_t)n * DIN))[r - 24];
        }
    }
    __syncthreads();

    float4 b4 = ((const float4*)brel)[fq];
    float4 acc0 = b4, acc1 = b4, acc2 = b4, acc3 = b4;
    const int n0 = nn * 4;

    for (int k = 0; k < DIN; k += 4) {
        float4 wr0 = ((const float4*)WrelT)[(k + 0) * 32 + fq];
        float4 wr1 = ((const float4*)WrelT)[(k + 1) * 32 + fq];
        float4 wr2 = ((const float4*)WrelT)[(k + 2) * 32 + fq];
        float4 wr3 = ((const float4*)WrelT)[(k + 3) * 32 + fq];
        float4 wo0 = ((const float4*)WrootT)[(k + 0) * 32 + fq];
        float4 wo1 = ((const float4*)WrootT)[(k + 1) * 32 + fq];
        float4 wo2 = ((const float4*)WrootT)[(k + 2) * 32 + fq];
        float4 wo3 = ((const float4*)WrootT)[(k + 3) * 32 + fq];
#define CSTEP(ACC, NODE)                                                      \
        {                                                                     \
            float4 a = *(const float4*)&sa[NODE][k];                          \
            float4 b = *(const float4*)&sx[NODE][k];                          \
            ACC.x = fmaf(a.x, wr0.x, ACC.x); ACC.x = fmaf(a.y, wr1.x, ACC.x); \
            ACC.x = fmaf(a.z, wr2.x, ACC.x); ACC.x = fmaf(a.w, wr3.x, ACC.x); \
            ACC.x = fmaf(b.x, wo0.x, ACC.x); ACC.x = fmaf(b.y, wo1.x, ACC.x); \
            ACC.x = fmaf(b.z, wo2.x, ACC.x); ACC.x = fmaf(b.w, wo3.x, ACC.x); \
            ACC.y = fmaf(a.x, wr0.y, ACC.y); ACC.y = fmaf(a.y, wr1.y, ACC.y); \
            ACC.y = fmaf(a.z, wr2.y, ACC.y); ACC.y = fmaf(a.w, wr3.y, ACC.y); \
            ACC.y = fmaf(b.x, wo0.y, ACC.y); ACC.y = fmaf(b.y, wo1.y, ACC.y); \
            ACC.y = fmaf(b.z, wo2.y, ACC.y); ACC.y = fmaf(b.w, wo3.y, ACC.y); \
            ACC.z = fmaf(a.x, wr0.z, ACC.z); ACC.z = fmaf(a.y, wr1.z, ACC.z); \
            ACC.z = fmaf(a.z, wr2.z, ACC.z); ACC.z = fmaf(a.w, wr3.z, ACC.z); \
            ACC.z = fmaf(b.x, wo0.z, ACC.z); ACC.z = fmaf(b.y, wo1.z, ACC.z); \
            ACC.z = fmaf(b.z, wo2.z, ACC.z); ACC.z = fmaf(b.w, wo3.z, ACC.z); \
            ACC.w = fmaf(a.x, wr0.w, ACC.w); ACC.w = fmaf(a.y, wr1.w, ACC.w); \
            ACC.w = fmaf(a.z, wr2.w, ACC.w); ACC.w = fmaf(a.w, wr3.w, ACC.w); \
            ACC.w = fmaf(b.x, wo0.w, ACC.w); ACC.w = fmaf(b.y, wo1.w, ACC.w); \
            ACC.w = fmaf(b.z, wo2.w, ACC.w); ACC.w = fmaf(b.w, wo3.w, ACC.w); \
        }
        CSTEP(acc0, n0 + 0)
        CSTEP(acc1, n0 + 1)
        CSTEP(acc2, n0 + 2)
        CSTEP(acc3, n0 + 3)
#undef CSTEP
    }

    // epilogue: relu, project onto u and v, reduce across the 32-lane group
    float4 u4 = ((const float4*)u)[fq];
    float4 v4 = ((const float4*)v)[fq];
#define EPI(ACC, C)                                                            \
    {                                                                          \
        ACC.x = fmaxf(ACC.x, 0.f); ACC.y = fmaxf(ACC.y, 0.f);                  \
        ACC.z = fmaxf(ACC.z, 0.f); ACC.w = fmaxf(ACC.w, 0.f);                  \
        float pp = ACC.x * u4.x + ACC.y * u4.y + ACC.z * u4.z + ACC.w * u4.w;  \
        float qq = ACC.x * v4.x + ACC.y * v4.y + ACC.z * v4.z + ACC.w * v4.w;  \
        for (int off = 16; off > 0; off >>= 1) {                               \
            pp += __shfl_xor(pp, off, 32);                                     \
            qq += __shfl_xor(qq, off, 32);                                     \
        }                                                                      \
        int n = base + n0 + C;                                                 \
        if (fq == 0 && n < NN) { p[n] = pp; q[n] = qq; }                       \
    }
    EPI(acc0, 0)
    EPI(acc1, 1)
    EPI(acc2, 2)
    EPI(acc3, 3)
#undef EPI
}

// ---------------------------------------------------------------------------
// Edge-level reduction: partialE[b][g] = sum over this block's edges of
// w_e * p[src_e] bucketed by g = batch[dst_e]. LDS buckets, no global atomics.
// ---------------------------------------------------------------------------
__launch_bounds__(256)
__global__ void edge_reduce_kernel(const int* __restrict__ ei,
                                   const float* __restrict__ ea,
                                   const float* __restrict__ p,
                                   const int* __restrict__ batch,
                                   float* __restrict__ partialE) {
    __shared__ float lb[NG];
    int tid = threadIdx.x;
    lb[tid] = 0.f;
    __syncthreads();
    for (int e = blockIdx.x * 256 + tid; e < NE; e += 256 * NBE) {
        int s = ei[e];
        int d = ei[NE + e];
        float val = ea[e] * p[s];
        atomicAdd(&lb[batch[d]], val);
    }
    __syncthreads();
    partialE[blockIdx.x * NG + tid] = lb[tid];
}

// ---------------------------------------------------------------------------
// Node-level reduction: per-graph sum of q and node counts.
// ---------------------------------------------------------------------------
__launch_bounds__(256)
__global__ void node_reduce_kernel(const float* __restrict__ q,
                                   const int* __restrict__ batch,
                                   float* __restrict__ partialQ,
                                   float* __restrict__ partialC) {
    __shared__ float lq[NG];
    __shared__ float lc[NG];
    int tid = threadIdx.x;
    lq[tid] = 0.f;
    lc[tid] = 0.f;
    __syncthreads();
    for (int i = blockIdx.x * 256 + tid; i < NN; i += 256 * NBN) {
        int g = batch[i];
        atomicAdd(&lq[g], q[i]);
        atomicAdd(&lc[g], 1.f);
    }
    __syncthreads();
    partialQ[blockIdx.x * NG + tid] = lq[tid];
    partialC[blockIdx.x * NG + tid] = lc[tid];
}

// ---------------------------------------------------------------------------
// Final: out_g = relu( (t_g + qs_g + n_g*c0)/max(n_g,1) + blin )
// ---------------------------------------------------------------------------
__global__ void final_kernel(const float* __restrict__ partialE,
                             const float* __restrict__ partialQ,
                             const float* __restrict__ partialC,
                             const float* __restrict__ c0,
                             const float* __restrict__ blin,
                             float* __restrict__ out) {
    int g = threadIdx.x;
    float t = 0.f;
    for (int b = 0; b < NBE; ++b) t += partialE[b * NG + g];
    float qs = 0.f, cn = 0.f;
    for (int b = 0; b < NBN; ++b) {
        qs += partialQ[b * NG + g];
        cn += partialC[b * NG + g];
    }
    float n = fmaxf(cn, 1.f);
    float val = (t + qs + cn * c0[0]) / n + blin[0];
    out[g] = fmaxf(val, 0.f);
}

// ---------------------------------------------------------------------------
extern "C" void kernel_launch(void* const* d_in, const int* in_sizes, int n_in,
                              void* d_out, int out_size, void* d_ws, size_t ws_size,
                              hipStream_t stream) {
    const float* x      = (const float*)d_in[0];
    const int*   ei     = (const int*)  d_in[1];   // [2, NE]
    const int*   batch  = (const int*)  d_in[2];
    const float* ea     = (const float*)d_in[3];
    const float* Wrel1  = (const float*)d_in[4];   // [HID, DIN]
    const float* brel1  = (const float*)d_in[5];
    const float* Wroot1 = (const float*)d_in[6];   // [HID, DIN]
    const float* Wrel3  = (const float*)d_in[7];   // [HID, HID]
    const float* brel3  = (const float*)d_in[8];
    const float* Wroot3 = (const float*)d_in[9];   // [HID, HID]
    const float* Wlin   = (const float*)d_in[10];  // [1, HID]
    const float* blin   = (const float*)d_in[11];
    float* out = (float*)d_out;

    // workspace layout (floats; every sub-array a multiple of 4 floats)
    float* ws = (float*)d_ws;
    float* agg1     = ws;                            // NN*DIN = 4,800,000
    float* WrelT1   = agg1 + (size_t)NN * DIN;       // 12,288
    float* WrootT1  = WrelT1 + DIN * HID;            // 12,288
    float* u        = WrootT1 + DIN * HID;           // 128
    float* v        = u + HID;                       // 128
    float* c0       = v + HID;                       // 4
    float* p        = c0 + 4;                        // 50,048 (padded)
    float* q        = p + 50048;                     // 50,048
    float* partialE = q + 50048;                     // NBE*NG = 65,536
    float* partialQ = partialE + NBE * NG;           // NBN*NG = 16,384
    float* partialC = partialQ + NBN * NG;           // 16,384
    int2*  csr_sw   = (int2*)(partialC + NBN * NG);  // NE*2 ints
    int*   row_ptr  = (int*)(csr_sw + NE);           // NN+1 (+pad)
    int*   deg      = row_ptr + NN + 4;              // NN
    int*   cursor   = deg + NN;                      // NN
    // total ~27 MB

    // --- CSR build ---
    zero_int_kernel<<<(NN + 255) / 256, 256, 0, stream>>>(deg, NN);
    hist_kernel<<<(NE + 255) / 256, 256, 0, stream>>>(ei, deg);
    scan_kernel<<<1, 1024, 0, stream>>>(deg, row_ptr, cursor);
    fill_kernel<<<(NE + 255) / 256, 256, 0, stream>>>(ei, ea, cursor, csr_sw);

    // --- weight prep (tiny) ---
    transpose_kernel<<<(HID * DIN + 255) / 256, 256, 0, stream>>>(Wrel1,  WrelT1,  HID, DIN);
    transpose_kernel<<<(HID * DIN + 255) / 256, 256, 0, stream>>>(Wroot1, WrootT1, HID, DIN);
    uv_kernel<<<1, HID, 0, stream>>>(Wrel3, Wroot3, Wlin, brel3, u, v, c0);

    // --- conv1 aggregation (gather, no atomics) ---
    gather1_kernel<<<(NN + 7) / 8, 256, 0, stream>>>(x, row_ptr, csr_sw, agg1);

    // --- conv1 GEMM + relu + scalar projections p,q ---
    conv1_kernel<<<(NN + 31) / 32, 256, 0, stream>>>(x, agg1, WrelT1, WrootT1,
                                                     brel1, u, v, p, q);

    // --- edge & node scalar reductions ---
    edge_reduce_kernel<<<NBE, 256, 0, stream>>>(ei, ea, p, batch, partialE);
    node_reduce_kernel<<<NBN, 256, 0, stream>>>(q, batch, partialQ, partialC);

    // --- final combine ---
    final_kernel<<<1, NG, 0, stream>>>(partialE, partialQ, partialC, c0, blin, out);
}

// Round 4
// 307.111 us; speedup vs baseline: 8.6762x; 1.3794x over previous
//
#include <hip/hip_runtime.h>

// Problem constants (from reference)
constexpr int NN  = 50000;   // nodes
constexpr int NE  = 800000;  // edges
constexpr int DIN = 96;      // input feature dim
constexpr int HID = 128;     // hidden dim
constexpr int NG  = 256;     // graphs

constexpr int NBE = 256;     // blocks for edge reduction
constexpr int NBN = 64;      // blocks for node reduction
constexpr int NBLK_SCAN = (NN + 255) / 256;  // 196 scan blocks

// ---------------------------------------------------------------------------
// zero-fill ints (deg histogram needs zeros; ws is poisoned 0xAA)
// ---------------------------------------------------------------------------
__global__ void zero_int_kernel(int* __restrict__ p, int n) {
    int i = blockIdx.x * blockDim.x + threadIdx.x;
    if (i < n) p[i] = 0;
}

// ---------------------------------------------------------------------------
// transpose W[rows][cols] -> WT[cols][rows] (tiny, one-shot per launch)
// ---------------------------------------------------------------------------
__global__ void transpose_kernel(const float* __restrict__ src,
                                 float* __restrict__ dst, int rows, int cols) {
    int i = blockIdx.x * blockDim.x + threadIdx.x;
    if (i >= rows * cols) return;
    int r = i / cols, c = i - r * cols;
    dst[c * rows + r] = src[i];
}

// ---------------------------------------------------------------------------
// u_k = sum_f Wlin[f] * Wrel3[f][k];  v_k = sum_f Wlin[f] * Wroot3[f][k]
// c0 = Wlin . b3   (128 threads, one block)
// ---------------------------------------------------------------------------
__global__ void uv_kernel(const float* __restrict__ Wrel3,
                          const float* __restrict__ Wroot3,
                          const float* __restrict__ Wlin,
                          const float* __restrict__ b3,
                          float* __restrict__ u, float* __restrict__ v,
                          float* __restrict__ c0) {
    int k = threadIdx.x;
    float su = 0.f, sv = 0.f;
    for (int f = 0; f < HID; ++f) {
        float wl = Wlin[f];
        su = fmaf(wl, Wrel3[f * HID + k], su);
        sv = fmaf(wl, Wroot3[f * HID + k], sv);
    }
    u[k] = su;
    v[k] = sv;
    if (k == 0) {
        float c = 0.f;
        for (int f = 0; f < HID; ++f) c = fmaf(Wlin[f], b3[f], c);
        c0[0] = c;
    }
}

// ---------------------------------------------------------------------------
// CSR build step 1: in-degree histogram over dst
// ---------------------------------------------------------------------------
__global__ void hist_kernel(const int* __restrict__ ei, int* __restrict__ deg) {
    int e = blockIdx.x * blockDim.x + threadIdx.x;
    if (e < NE) atomicAdd(&deg[ei[NE + e]], 1);
}

// ---------------------------------------------------------------------------
// CSR scan stage 1: per-block sums of deg (256 elems per block)
// ---------------------------------------------------------------------------
__launch_bounds__(256)
__global__ void scan1_kernel(const int* __restrict__ deg, int* __restrict__ blockSums) {
    __shared__ int s[256];
    int t = threadIdx.x;
    int idx = blockIdx.x * 256 + t;
    s[t] = (idx < NN) ? deg[idx] : 0;
    __syncthreads();
    for (int off = 128; off > 0; off >>= 1) {
        if (t < off) s[t] += s[t + off];
        __syncthreads();
    }
    if (t == 0) blockSums[blockIdx.x] = s[0];
}

// ---------------------------------------------------------------------------
// CSR scan stage 2: exclusive scan of the 196 block sums (one tiny block)
// Also writes row_ptr[NN] = total (== NE).
// ---------------------------------------------------------------------------
__launch_bounds__(256)
__global__ void scan2_kernel(const int* __restrict__ blockSums,
                             int* __restrict__ blockOff,
                             int* __restrict__ row_ptr) {
    __shared__ int s[256];
    int t = threadIdx.x;
    s[t] = (t < NBLK_SCAN) ? blockSums[t] : 0;
    __syncthreads();
    // Hillis-Steele inclusive scan over 256
    for (int off = 1; off < 256; off <<= 1) {
        int v = (t >= off) ? s[t - off] : 0;
        __syncthreads();
        s[t] += v;
        __syncthreads();
    }
    if (t < NBLK_SCAN) blockOff[t] = (t == 0) ? 0 : s[t - 1];
    if (t == NBLK_SCAN - 1) row_ptr[NN] = s[t];
}

// ---------------------------------------------------------------------------
// CSR scan stage 3: per-block exclusive scan + block offset -> row_ptr, cursor
// ---------------------------------------------------------------------------
__launch_bounds__(256)
__global__ void scan3_kernel(const int* __restrict__ deg,
                             const int* __restrict__ blockOff,
                             int* __restrict__ row_ptr,
                             int* __restrict__ cursor) {
    __shared__ int s[256];
    int t = threadIdx.x;
    int idx = blockIdx.x * 256 + t;
    int d = (idx < NN) ? deg[idx] : 0;
    s[t] = d;
    __syncthreads();
    for (int off = 1; off < 256; off <<= 1) {
        int v = (t >= off) ? s[t - off] : 0;
        __syncthreads();
        s[t] += v;
        __syncthreads();
    }
    if (idx < NN) {
        int val = blockOff[blockIdx.x] + s[t] - d;  // exclusive
        row_ptr[idx] = val;
        cursor[idx]  = val;
    }
}

// ---------------------------------------------------------------------------
// CSR build step 3: fill (src, weight) pairs grouped by dst, packed 8B
// ---------------------------------------------------------------------------
__global__ void fill_kernel(const int* __restrict__ ei, const float* __restrict__ ea,
                            int* __restrict__ cursor, int2* __restrict__ csr_sw) {
    int e = blockIdx.x * blockDim.x + threadIdx.x;
    if (e >= NE) return;
    int dst = ei[NE + e];
    int pos = atomicAdd(&cursor[dst], 1);
    csr_sw[pos] = make_int2(ei[e], __float_as_int(ea[e]));
}

// ---------------------------------------------------------------------------
// conv1 aggregation, gather form: agg1[n] = sum_{e: dst=n} w_e * x[src_e]
// 32 lanes per node, 3 feats/lane, 2-edge unroll for MLP. No atomics.
// ---------------------------------------------------------------------------
__launch_bounds__(256)
__global__ void gather1_kernel(const float* __restrict__ x,
                               const int* __restrict__ row_ptr,
                               const int2* __restrict__ csr_sw,
                               float* __restrict__ agg) {
    int node = blockIdx.x * 8 + (threadIdx.x >> 5);
    int lane = threadIdx.x & 31;
    if (node >= NN) return;
    int s = row_ptr[node], t = row_ptr[node + 1];
    float a0 = 0.f, a1 = 0.f, a2 = 0.f;
    int j = s;
    for (; j + 1 < t; j += 2) {
        int2 e0 = csr_sw[j];
        int2 e1 = csr_sw[j + 1];
        float w0 = __int_as_float(e0.y);
        float w1 = __int_as_float(e1.y);
        const float* x0 = x + (size_t)e0.x * DIN + lane;
        const float* x1 = x + (size_t)e1.x * DIN + lane;
        a0 = fmaf(w0, x0[0],  a0);
        a1 = fmaf(w0, x0[32], a1);
        a2 = fmaf(w0, x0[64], a2);
        a0 = fmaf(w1, x1[0],  a0);
        a1 = fmaf(w1, x1[32], a1);
        a2 = fmaf(w1, x1[64], a2);
    }
    if (j < t) {
        int2 e0 = csr_sw[j];
        float w0 = __int_as_float(e0.y);
        const float* x0 = x + (size_t)e0.x * DIN + lane;
        a0 = fmaf(w0, x0[0],  a0);
        a1 = fmaf(w0, x0[32], a1);
        a2 = fmaf(w0, x0[64], a2);
    }
    float* ap = agg + (size_t)node * DIN + lane;
    ap[0]  = a0;
    ap[32] = a1;
    ap[64] = a2;
}

// ---------------------------------------------------------------------------
// conv1 GEMM + relu + projection to scalars:
//   h1row = relu(agg1 @ Wrel1^T + b1 + x @ Wroot1^T)   (in registers only)
//   p[n] = u . h1row ; q[n] = v . h1row
// ---------------------------------------------------------------------------
__launch_bounds__(256)
__global__ void conv1_kernel(const float* __restrict__ x,
                             const float* __restrict__ agg,
                             const float* __restrict__ WrelT,   // [DIN][HID]
                             const float* __restrict__ WrootT,  // [DIN][HID]
                             const float* __restrict__ brel,
                             const float* __restrict__ u,
                             const float* __restrict__ v,
                             float* __restrict__ p,
                             float* __restrict__ q) {
    __shared__ float sx[32][DIN];
    __shared__ float sa[32][DIN];
    const int tid = threadIdx.x;
    const int nn = tid >> 5;     // 0..7, owns nodes 4nn..4nn+3
    const int fq = tid & 31;     // feature quad 0..31
    const int base = blockIdx.x * 32;

    for (int j = tid; j < 32 * 48; j += 256) {
        int node = j / 48;
        int r = j - node * 48;
        int n = base + node;
        if (n < NN) {
            if (r < 24) ((float4*)sx[node])[r]      = ((const float4*)(x   + (size_t)n * DIN))[r];
            else        ((float4*)sa[node])[r - 24] = ((const float4*)(agg + (size_t)n * DIN))[r - 24];
        }
    }
    __syncthreads();

    float4 b4 = ((const float4*)brel)[fq];
    float4 acc0 = b4, acc1 = b4, acc2 = b4, acc3 = b4;
    const int n0 = nn * 4;

    for (int k = 0; k < DIN; k += 4) {
        float4 wr0 = ((const float4*)WrelT)[(k + 0) * 32 + fq];
        float4 wr1 = ((const float4*)WrelT)[(k + 1) * 32 + fq];
        float4 wr2 = ((const float4*)WrelT)[(k + 2) * 32 + fq];
        float4 wr3 = ((const float4*)WrelT)[(k + 3) * 32 + fq];
        float4 wo0 = ((const float4*)WrootT)[(k + 0) * 32 + fq];
        float4 wo1 = ((const float4*)WrootT)[(k + 1) * 32 + fq];
        float4 wo2 = ((const float4*)WrootT)[(k + 2) * 32 + fq];
        float4 wo3 = ((const float4*)WrootT)[(k + 3) * 32 + fq];
#define CSTEP(ACC, NODE)                                                      \
        {                                                                     \
            float4 a = *(const float4*)&sa[NODE][k];                          \
            float4 b = *(const float4*)&sx[NODE][k];                          \
            ACC.x = fmaf(a.x, wr0.x, ACC.x); ACC.x = fmaf(a.y, wr1.x, ACC.x); \
            ACC.x = fmaf(a.z, wr2.x, ACC.x); ACC.x = fmaf(a.w, wr3.x, ACC.x); \
            ACC.x = fmaf(b.x, wo0.x, ACC.x); ACC.x = fmaf(b.y, wo1.x, ACC.x); \
            ACC.x = fmaf(b.z, wo2.x, ACC.x); ACC.x = fmaf(b.w, wo3.x, ACC.x); \
            ACC.y = fmaf(a.x, wr0.y, ACC.y); ACC.y = fmaf(a.y, wr1.y, ACC.y); \
            ACC.y = fmaf(a.z, wr2.y, ACC.y); ACC.y = fmaf(a.w, wr3.y, ACC.y); \
            ACC.y = fmaf(b.x, wo0.y, ACC.y); ACC.y = fmaf(b.y, wo1.y, ACC.y); \
            ACC.y = fmaf(b.z, wo2.y, ACC.y); ACC.y = fmaf(b.w, wo3.y, ACC.y); \
            ACC.z = fmaf(a.x, wr0.z, ACC.z); ACC.z = fmaf(a.y, wr1.z, ACC.z); \
            ACC.z = fmaf(a.z, wr2.z, ACC.z); ACC.z = fmaf(a.w, wr3.z, ACC.z); \
            ACC.z = fmaf(b.x, wo0.z, ACC.z); ACC.z = fmaf(b.y, wo1.z, ACC.z); \
            ACC.z = fmaf(b.z, wo2.z, ACC.z); ACC.z = fmaf(b.w, wo3.z, ACC.z); \
            ACC.w = fmaf(a.x, wr0.w, ACC.w); ACC.w = fmaf(a.y, wr1.w, ACC.w); \
            ACC.w = fmaf(a.z, wr2.w, ACC.w); ACC.w = fmaf(a.w, wr3.w, ACC.w); \
            ACC.w = fmaf(b.x, wo0.w, ACC.w); ACC.w = fmaf(b.y, wo1.w, ACC.w); \
            ACC.w = fmaf(b.z, wo2.w, ACC.w); ACC.w = fmaf(b.w, wo3.w, ACC.w); \
        }
        CSTEP(acc0, n0 + 0)
        CSTEP(acc1, n0 + 1)
        CSTEP(acc2, n0 + 2)
        CSTEP(acc3, n0 + 3)
#undef CSTEP
    }

    float4 u4 = ((const float4*)u)[fq];
    float4 v4 = ((const float4*)v)[fq];
#define EPI(ACC, C)                                                            \
    {                                                                          \
        ACC.x = fmaxf(ACC.x, 0.f); ACC.y = fmaxf(ACC.y, 0.f);                  \
        ACC.z = fmaxf(ACC.z, 0.f); ACC.w = fmaxf(ACC.w, 0.f);                  \
        float pp = ACC.x * u4.x + ACC.y * u4.y + ACC.z * u4.z + ACC.w * u4.w;  \
        float qq = ACC.x * v4.x + ACC.y * v4.y + ACC.z * v4.z + ACC.w * v4.w;  \
        for (int off = 16; off > 0; off >>= 1) {                               \
            pp += __shfl_xor(pp, off, 32);                                     \
            qq += __shfl_xor(qq, off, 32);                                     \
        }                                                                      \
        int n = base + n0 + C;                                                 \
        if (fq == 0 && n < NN) { p[n] = pp; q[n] = qq; }                       \
    }
    EPI(acc0, 0)
    EPI(acc1, 1)
    EPI(acc2, 2)
    EPI(acc3, 3)
#undef EPI
}

// ---------------------------------------------------------------------------
// Edge-level reduction: partialE[b][g] = sum over this block's edges of
// w_e * p[src_e] bucketed by g = batch[dst_e]. LDS buckets, no global atomics.
// ---------------------------------------------------------------------------
__launch_bounds__(256)
__global__ void edge_reduce_kernel(const int* __restrict__ ei,
                                   const float* __restrict__ ea,
                                   const float* __restrict__ p,
                                   const int* __restrict__ batch,
                                   float* __restrict__ partialE) {
    __shared__ float lb[NG];
    int tid = threadIdx.x;
    lb[tid] = 0.f;
    __syncthreads();
    for (int e = blockIdx.x * 256 + tid; e < NE; e += 256 * NBE) {
        int s = ei[e];
        int d = ei[NE + e];
        float val = ea[e] * p[s];
        atomicAdd(&lb[batch[d]], val);
    }
    __syncthreads();
    partialE[blockIdx.x * NG + tid] = lb[tid];
}

// ---------------------------------------------------------------------------
// Node-level reduction: per-graph sum of q and node counts.
// ---------------------------------------------------------------------------
__launch_bounds__(256)
__global__ void node_reduce_kernel(const float* __restrict__ q,
                                   const int* __restrict__ batch,
                                   float* __restrict__ partialQ,
                                   float* __restrict__ partialC) {
    __shared__ float lq[NG];
    __shared__ float lc[NG];
    int tid = threadIdx.x;
    lq[tid] = 0.f;
    lc[tid] = 0.f;
    __syncthreads();
    for (int i = blockIdx.x * 256 + tid; i < NN; i += 256 * NBN) {
        int g = batch[i];
        atomicAdd(&lq[g], q[i]);
        atomicAdd(&lc[g], 1.f);
    }
    __syncthreads();
    partialQ[blockIdx.x * NG + tid] = lq[tid];
    partialC[blockIdx.x * NG + tid] = lc[tid];
}

// ---------------------------------------------------------------------------
// Final: out_g = relu( (t_g + qs_g)/max(n_g,1) + c0 + blin ) (cn>0 case folds)
// ---------------------------------------------------------------------------
__global__ void final_kernel(const float* __restrict__ partialE,
                             const float* __restrict__ partialQ,
                             const float* __restrict__ partialC,
                             const float* __restrict__ c0,
                             const float* __restrict__ blin,
                             float* __restrict__ out) {
    int g = threadIdx.x;
    float t = 0.f;
    for (int b = 0; b < NBE; ++b) t += partialE[b * NG + g];
    float qs = 0.f, cn = 0.f;
    for (int b = 0; b < NBN; ++b) {
        qs += partialQ[b * NG + g];
        cn += partialC[b * NG + g];
    }
    float n = fmaxf(cn, 1.f);
    float val = (t + qs + cn * c0[0]) / n + blin[0];
    out[g] = fmaxf(val, 0.f);
}

// ---------------------------------------------------------------------------
extern "C" void kernel_launch(void* const* d_in, const int* in_sizes, int n_in,
                              void* d_out, int out_size, void* d_ws, size_t ws_size,
                              hipStream_t stream) {
    const float* x      = (const float*)d_in[0];
    const int*   ei     = (const int*)  d_in[1];   // [2, NE]
    const int*   batch  = (const int*)  d_in[2];
    const float* ea     = (const float*)d_in[3];
    const float* Wrel1  = (const float*)d_in[4];   // [HID, DIN]
    const float* brel1  = (const float*)d_in[5];
    const float* Wroot1 = (const float*)d_in[6];   // [HID, DIN]
    const float* Wrel3  = (const float*)d_in[7];   // [HID, HID]
    const float* brel3  = (const float*)d_in[8];
    const float* Wroot3 = (const float*)d_in[9];   // [HID, HID]
    const float* Wlin   = (const float*)d_in[10];  // [1, HID]
    const float* blin   = (const float*)d_in[11];
    float* out = (float*)d_out;

    // workspace layout (floats; every sub-array a multiple of 4 floats)
    float* ws = (float*)d_ws;
    float* agg1     = ws;                            // NN*DIN = 4,800,000
    float* WrelT1   = agg1 + (size_t)NN * DIN;       // 12,288
    float* WrootT1  = WrelT1 + DIN * HID;            // 12,288
    float* u        = WrootT1 + DIN * HID;           // 128
    float* v        = u + HID;                       // 128
    float* c0       = v + HID;                       // 4
    float* p        = c0 + 4;                        // 50,048 (padded)
    float* q        = p + 50048;                     // 50,048
    float* partialE = q + 50048;                     // NBE*NG = 65,536
    float* partialQ = partialE + NBE * NG;           // NBN*NG = 16,384
    float* partialC = partialQ + NBN * NG;           // 16,384
    int2*  csr_sw   = (int2*)(partialC + NBN * NG);  // NE*2 ints
    int*   row_ptr  = (int*)(csr_sw + NE);           // NN+1 (+pad)
    int*   deg      = row_ptr + NN + 4;              // NN
    int*   cursor   = deg + NN;                      // NN
    int*   blockSums= cursor + NN;                   // 256
    int*   blockOff = blockSums + 256;               // 256
    // total ~27 MB

    // --- CSR build ---
    zero_int_kernel<<<(NN + 255) / 256, 256, 0, stream>>>(deg, NN);
    hist_kernel<<<(NE + 255) / 256, 256, 0, stream>>>(ei, deg);
    scan1_kernel<<<NBLK_SCAN, 256, 0, stream>>>(deg, blockSums);
    scan2_kernel<<<1, 256, 0, stream>>>(blockSums, blockOff, row_ptr);
    scan3_kernel<<<NBLK_SCAN, 256, 0, stream>>>(deg, blockOff, row_ptr, cursor);
    fill_kernel<<<(NE + 255) / 256, 256, 0, stream>>>(ei, ea, cursor, csr_sw);

    // --- weight prep (tiny) ---
    transpose_kernel<<<(HID * DIN + 255) / 256, 256, 0, stream>>>(Wrel1,  WrelT1,  HID, DIN);
    transpose_kernel<<<(HID * DIN + 255) / 256, 256, 0, stream>>>(Wroot1, WrootT1, HID, DIN);
    uv_kernel<<<1, HID, 0, stream>>>(Wrel3, Wroot3, Wlin, brel3, u, v, c0);

    // --- conv1 aggregation (gather, no atomics) ---
    gather1_kernel<<<(NN + 7) / 8, 256, 0, stream>>>(x, row_ptr, csr_sw, agg1);

    // --- conv1 GEMM + relu + scalar projections p,q ---
    conv1_kernel<<<(NN + 31) / 32, 256, 0, stream>>>(x, agg1, WrelT1, WrootT1,
                                                     brel1, u, v, p, q);

    // --- edge & node scalar reductions ---
    edge_reduce_kernel<<<NBE, 256, 0, stream>>>(ei, ea, p, batch, partialE);
    node_reduce_kernel<<<NBN, 256, 0, stream>>>(q, batch, partialQ, partialC);

    // --- final combine ---
    final_kernel<<<1, NG, 0, stream>>>(partialE, partialQ, partialC, c0, blin, out);
}